// Round 1
// baseline (4623.565 us; speedup 1.0000x reference)
//
#include <hip/hip_runtime.h>
#include <math.h>

#define B_ 16
#define T_ 64
#define N_ 512
#define H_ 128
#define P_ 12
#define NH 65536  // N_*H_

// ---------------------------------------------------------------------------
// Lx[b,t,m] = sum_n L[m,n] * x[b,t,n]   (uses L symmetric: L[m,n]=L[n,m] up to 1 ulp)
// grid 256 blocks (4 rows each of the 1024 (b,t) rows), 512 threads (one m each)
// ---------------------------------------------------------------------------
__global__ __launch_bounds__(512) void lx_kernel(const float* __restrict__ x,
                                                 const float* __restrict__ L,
                                                 float* __restrict__ Lx) {
    __shared__ __align__(16) float xs[4][N_];
    const int r0 = blockIdx.x * 4;
    const int tid = threadIdx.x;
    for (int j = 0; j < 4; ++j)
        xs[j][tid] = x[(size_t)(r0 + j) * N_ + tid];
    __syncthreads();
    float a0 = 0.f, a1 = 0.f, a2 = 0.f, a3 = 0.f;
    const int m = tid;
#pragma unroll 4
    for (int n = 0; n < N_; ++n) {
        float lv = L[(size_t)n * N_ + m];
        a0 += xs[0][n] * lv;
        a1 += xs[1][n] * lv;
        a2 += xs[2][n] * lv;
        a3 += xs[3][n] * lv;
    }
    Lx[(size_t)(r0 + 0) * N_ + m] = a0;
    Lx[(size_t)(r0 + 1) * N_ + m] = a1;
    Lx[(size_t)(r0 + 2) * N_ + m] = a2;
    Lx[(size_t)(r0 + 3) * N_ + m] = a3;
}

// ---------------------------------------------------------------------------
// Kernel A (graph_conv1 + sigmoid + split):
//   Z[b,m,ch] = sum_n L[m,n]*Hprev[b,n,ch]
//   ru[b,m,o] = sigmoid( Z[b,m,:]@W1[1:,o] + Lx[b,t,m]*W1[0,o] + b1[o] )
//   flat = m*256+o; flat<65536 -> rh[flat] = ru*Hprev_flat[flat]; else u[flat-65536] = ru
// grid = 16 b * 16 mtiles(32), 512 threads, intra-block K-split x2
// ---------------------------------------------------------------------------
__global__ __launch_bounds__(512) void gc1_kernel(
    const float* __restrict__ L, const float* __restrict__ Hprev,
    const float* __restrict__ Lx, const float* __restrict__ W1,
    const float* __restrict__ b1, float* __restrict__ rh,
    float* __restrict__ u, int t) {
    __shared__ __align__(16) float Lt[2][32][36];
    __shared__ __align__(16) float Ht[2][32][H_];
    __shared__ __align__(16) float Zs[2][32][H_];

    const int tid = threadIdx.x;
    const int b = blockIdx.x >> 4;
    const int m0 = (blockIdx.x & 15) * 32;
    const int g = tid >> 8;       // K-group 0/1
    const int gtid = tid & 255;

    const float* __restrict__ Hb = Hprev + (size_t)b * NH;

    // ---- phase 1: Z = L @ Hprev (this block's 32 rows, this group's 256 Ks)
    float acc[4][4];
#pragma unroll
    for (int i = 0; i < 4; ++i)
#pragma unroll
        for (int j = 0; j < 4; ++j) acc[i][j] = 0.f;

    const int tx = gtid & 31, ty = gtid >> 5;
    const int ch0 = tx * 4;
    const int lr = gtid >> 3, lc = (gtid & 7) * 4;

    for (int kc = 0; kc < 8; ++kc) {
        const int kbase = g * 256 + kc * 32;
        // stage L tile 32x32 (padded rows)
        float4 lv = *(const float4*)&L[(size_t)(m0 + lr) * N_ + kbase + lc];
        Lt[g][lr][lc + 0] = lv.x;
        Lt[g][lr][lc + 1] = lv.y;
        Lt[g][lr][lc + 2] = lv.z;
        Lt[g][lr][lc + 3] = lv.w;
        // stage H tile 32x128
#pragma unroll
        for (int j = 0; j < 4; ++j) {
            int f = gtid + 256 * j;
            int k = f >> 5, c = (f & 31) * 4;
            *(float4*)&Ht[g][k][c] = *(const float4*)&Hb[(size_t)(kbase + k) * H_ + c];
        }
        __syncthreads();
#pragma unroll
        for (int k4 = 0; k4 < 8; ++k4) {
            float4 h0v = *(const float4*)&Ht[g][k4 * 4 + 0][ch0];
            float4 h1v = *(const float4*)&Ht[g][k4 * 4 + 1][ch0];
            float4 h2v = *(const float4*)&Ht[g][k4 * 4 + 2][ch0];
            float4 h3v = *(const float4*)&Ht[g][k4 * 4 + 3][ch0];
#pragma unroll
            for (int i = 0; i < 4; ++i) {
                float4 lf = *(const float4*)&Lt[g][ty + 8 * i][k4 * 4];
                acc[i][0] += lf.x * h0v.x + lf.y * h1v.x + lf.z * h2v.x + lf.w * h3v.x;
                acc[i][1] += lf.x * h0v.y + lf.y * h1v.y + lf.z * h2v.y + lf.w * h3v.y;
                acc[i][2] += lf.x * h0v.z + lf.y * h1v.z + lf.z * h2v.z + lf.w * h3v.z;
                acc[i][3] += lf.x * h0v.w + lf.y * h1v.w + lf.z * h2v.w + lf.w * h3v.w;
            }
        }
        __syncthreads();
    }
#pragma unroll
    for (int i = 0; i < 4; ++i)
        *(float4*)&Zs[g][ty + 8 * i][ch0] =
            make_float4(acc[i][0], acc[i][1], acc[i][2], acc[i][3]);
    __syncthreads();

    // ---- phase 2: out = (Z0+Z1) @ W1[1:,:] ; epilogue sigmoid + split
    const int to = tid & 63, tm = tid >> 6;  // o0 in [0,256), 8 m-groups (wave-uniform tm)
    const int o0 = to * 4;
    float a2[4][4];
#pragma unroll
    for (int i = 0; i < 4; ++i)
#pragma unroll
        for (int j = 0; j < 4; ++j) a2[i][j] = 0.f;

    for (int ch = 0; ch < H_; ch += 4) {
        float4 w0v = *(const float4*)&W1[(size_t)(1 + ch + 0) * 256 + o0];
        float4 w1v = *(const float4*)&W1[(size_t)(1 + ch + 1) * 256 + o0];
        float4 w2v = *(const float4*)&W1[(size_t)(1 + ch + 2) * 256 + o0];
        float4 w3v = *(const float4*)&W1[(size_t)(1 + ch + 3) * 256 + o0];
#pragma unroll
        for (int i = 0; i < 4; ++i) {
            const int mi = tm + 8 * i;
            float4 za = *(const float4*)&Zs[0][mi][ch];
            float4 zb = *(const float4*)&Zs[1][mi][ch];
            float zx = za.x + zb.x, zy = za.y + zb.y, zz = za.z + zb.z, zw = za.w + zb.w;
            a2[i][0] += zx * w0v.x + zy * w1v.x + zz * w2v.x + zw * w3v.x;
            a2[i][1] += zx * w0v.y + zy * w1v.y + zz * w2v.y + zw * w3v.y;
            a2[i][2] += zx * w0v.z + zy * w1v.z + zz * w2v.z + zw * w3v.z;
            a2[i][3] += zx * w0v.w + zy * w1v.w + zz * w2v.w + zw * w3v.w;
        }
    }

    const float4 w0r = *(const float4*)&W1[o0];   // row 0 (x channel)
    const float4 bbv = *(const float4*)&b1[o0];
    const float* __restrict__ LxRow = Lx + ((size_t)b * T_ + t) * N_ + m0;
    float* __restrict__ rhB = rh + (size_t)b * NH;
    float* __restrict__ uB = u + (size_t)b * NH;
    const bool isR = (m0 < 256);  // whole 32-tile is on one side of the split
#pragma unroll
    for (int i = 0; i < 4; ++i) {
        const int mi = tm + 8 * i;
        const float lx = LxRow[mi];
        float v0 = a2[i][0] + lx * w0r.x + bbv.x;
        float v1 = a2[i][1] + lx * w0r.y + bbv.y;
        float v2 = a2[i][2] + lx * w0r.z + bbv.z;
        float v3 = a2[i][3] + lx * w0r.w + bbv.w;
        float s0 = 1.f / (1.f + expf(-v0));
        float s1 = 1.f / (1.f + expf(-v1));
        float s2 = 1.f / (1.f + expf(-v2));
        float s3 = 1.f / (1.f + expf(-v3));
        const int fl = (m0 + mi) * 256 + o0;
        if (isR) {
            float4 hv = *(const float4*)&Hb[fl];
            *(float4*)&rhB[fl] = make_float4(s0 * hv.x, s1 * hv.y, s2 * hv.z, s3 * hv.w);
        } else {
            *(float4*)&uB[fl - NH] = make_float4(s0, s1, s2, s3);
        }
    }
}

// ---------------------------------------------------------------------------
// Kernel B (graph_conv2 + tanh + GRU blend + hs1 row-reduction):
//   Z[b,m,ch] = sum_n L[m,n]*rh[b,n,ch]
//   c[m,o]    = tanh( Z@W2[1:,o] + Lx*W2[0,o] + b2[o] )
//   hn        = u*hprev + (1-u)*c   (all flat [N*H])
//   hs1[b,t,m] = sum_o hn[m,o]*att_w1[o] + att_b1
// ---------------------------------------------------------------------------
__global__ __launch_bounds__(512) void gc2_kernel(
    const float* __restrict__ L, const float* __restrict__ Hprev,
    const float* __restrict__ rh, const float* __restrict__ u,
    const float* __restrict__ Lx, const float* __restrict__ W2,
    const float* __restrict__ b2, const float* __restrict__ aw1,
    const float* __restrict__ ab1, float* __restrict__ Hnew,
    float* __restrict__ hs1, int t) {
    __shared__ __align__(16) float Lt[2][32][36];
    __shared__ __align__(16) float Ht[2][32][H_];
    __shared__ __align__(16) float Zs[2][32][H_];
    __shared__ __align__(16) float red[32][32];

    const int tid = threadIdx.x;
    const int b = blockIdx.x >> 4;
    const int m0 = (blockIdx.x & 15) * 32;
    const int g = tid >> 8;
    const int gtid = tid & 255;

    const float* __restrict__ Rb = rh + (size_t)b * NH;
    const float* __restrict__ Hb = Hprev + (size_t)b * NH;
    const float* __restrict__ Ub = u + (size_t)b * NH;

    float acc[4][4];
#pragma unroll
    for (int i = 0; i < 4; ++i)
#pragma unroll
        for (int j = 0; j < 4; ++j) acc[i][j] = 0.f;

    const int tx = gtid & 31, ty = gtid >> 5;
    const int ch0 = tx * 4;
    const int lr = gtid >> 3, lc = (gtid & 7) * 4;

    for (int kc = 0; kc < 8; ++kc) {
        const int kbase = g * 256 + kc * 32;
        float4 lv = *(const float4*)&L[(size_t)(m0 + lr) * N_ + kbase + lc];
        Lt[g][lr][lc + 0] = lv.x;
        Lt[g][lr][lc + 1] = lv.y;
        Lt[g][lr][lc + 2] = lv.z;
        Lt[g][lr][lc + 3] = lv.w;
#pragma unroll
        for (int j = 0; j < 4; ++j) {
            int f = gtid + 256 * j;
            int k = f >> 5, c = (f & 31) * 4;
            *(float4*)&Ht[g][k][c] = *(const float4*)&Rb[(size_t)(kbase + k) * H_ + c];
        }
        __syncthreads();
#pragma unroll
        for (int k4 = 0; k4 < 8; ++k4) {
            float4 h0v = *(const float4*)&Ht[g][k4 * 4 + 0][ch0];
            float4 h1v = *(const float4*)&Ht[g][k4 * 4 + 1][ch0];
            float4 h2v = *(const float4*)&Ht[g][k4 * 4 + 2][ch0];
            float4 h3v = *(const float4*)&Ht[g][k4 * 4 + 3][ch0];
#pragma unroll
            for (int i = 0; i < 4; ++i) {
                float4 lf = *(const float4*)&Lt[g][ty + 8 * i][k4 * 4];
                acc[i][0] += lf.x * h0v.x + lf.y * h1v.x + lf.z * h2v.x + lf.w * h3v.x;
                acc[i][1] += lf.x * h0v.y + lf.y * h1v.y + lf.z * h2v.y + lf.w * h3v.y;
                acc[i][2] += lf.x * h0v.z + lf.y * h1v.z + lf.z * h2v.z + lf.w * h3v.z;
                acc[i][3] += lf.x * h0v.w + lf.y * h1v.w + lf.z * h2v.w + lf.w * h3v.w;
            }
        }
        __syncthreads();
    }
#pragma unroll
    for (int i = 0; i < 4; ++i)
        *(float4*)&Zs[g][ty + 8 * i][ch0] =
            make_float4(acc[i][0], acc[i][1], acc[i][2], acc[i][3]);
    __syncthreads();

    // phase 2: o range 128
    const int to = tid & 31, tm = tid >> 5;  // 16 m-groups, 2 m each
    const int o0 = to * 4;
    float a2[2][4];
#pragma unroll
    for (int i = 0; i < 2; ++i)
#pragma unroll
        for (int j = 0; j < 4; ++j) a2[i][j] = 0.f;

    for (int ch = 0; ch < H_; ch += 4) {
        float4 w0v = *(const float4*)&W2[(size_t)(1 + ch + 0) * H_ + o0];
        float4 w1v = *(const float4*)&W2[(size_t)(1 + ch + 1) * H_ + o0];
        float4 w2v = *(const float4*)&W2[(size_t)(1 + ch + 2) * H_ + o0];
        float4 w3v = *(const float4*)&W2[(size_t)(1 + ch + 3) * H_ + o0];
#pragma unroll
        for (int i = 0; i < 2; ++i) {
            const int mi = tm + 16 * i;
            float4 za = *(const float4*)&Zs[0][mi][ch];
            float4 zb = *(const float4*)&Zs[1][mi][ch];
            float zx = za.x + zb.x, zy = za.y + zb.y, zz = za.z + zb.z, zw = za.w + zb.w;
            a2[i][0] += zx * w0v.x + zy * w1v.x + zz * w2v.x + zw * w3v.x;
            a2[i][1] += zx * w0v.y + zy * w1v.y + zz * w2v.y + zw * w3v.y;
            a2[i][2] += zx * w0v.z + zy * w1v.z + zz * w2v.z + zw * w3v.z;
            a2[i][3] += zx * w0v.w + zy * w1v.w + zz * w2v.w + zw * w3v.w;
        }
    }

    const float4 w0r = *(const float4*)&W2[o0];
    const float4 bbv = *(const float4*)&b2[o0];
    const float4 awv = *(const float4*)&aw1[o0];
    const float* __restrict__ LxRow = Lx + ((size_t)b * T_ + t) * N_ + m0;
    float* __restrict__ HnB = Hnew + (size_t)b * NH;
#pragma unroll
    for (int i = 0; i < 2; ++i) {
        const int mi = tm + 16 * i;
        const float lx = LxRow[mi];
        float c0 = tanhf(a2[i][0] + lx * w0r.x + bbv.x);
        float c1 = tanhf(a2[i][1] + lx * w0r.y + bbv.y);
        float c2 = tanhf(a2[i][2] + lx * w0r.z + bbv.z);
        float c3 = tanhf(a2[i][3] + lx * w0r.w + bbv.w);
        const int fl = (m0 + mi) * H_ + o0;
        float4 uv = *(const float4*)&Ub[fl];
        float4 hp = *(const float4*)&Hb[fl];
        float h0 = uv.x * hp.x + (1.f - uv.x) * c0;
        float h1 = uv.y * hp.y + (1.f - uv.y) * c1;
        float h2 = uv.z * hp.z + (1.f - uv.z) * c2;
        float h3 = uv.w * hp.w + (1.f - uv.w) * c3;
        *(float4*)&HnB[fl] = make_float4(h0, h1, h2, h3);
        red[mi][to] = h0 * awv.x + h1 * awv.y + h2 * awv.z + h3 * awv.w;
    }
    __syncthreads();
    if (tid < 32) {
        float s = 0.f;
#pragma unroll
        for (int k2 = 0; k2 < 32; ++k2) s += red[tid][k2];
        hs1[((size_t)b * T_ + t) * N_ + m0 + tid] = s + ab1[0];
    }
}

// ---------------------------------------------------------------------------
// beta[b,t] = softmax_t( (hs1[b,t,:]@aw2+ab2) * (hs1[b,t,:]@aw3+ab3) )
// grid 16 blocks, 64 threads (one wave; lane = t)
// ---------------------------------------------------------------------------
__global__ __launch_bounds__(64) void att_beta_kernel(
    const float* __restrict__ hs1, const float* __restrict__ aw2,
    const float* __restrict__ aw3, const float* __restrict__ ab2,
    const float* __restrict__ ab3, float* __restrict__ beta) {
    const int b = blockIdx.x;
    const int t = threadIdx.x;
    const float* __restrict__ row = hs1 + ((size_t)b * T_ + t) * N_;
    float f = 0.f, g = 0.f;
    for (int n = 0; n < N_; n += 4) {
        float4 hv = *(const float4*)&row[n];
        float4 w2v = *(const float4*)&aw2[n];
        float4 w3v = *(const float4*)&aw3[n];
        f += hv.x * w2v.x + hv.y * w2v.y + hv.z * w2v.z + hv.w * w2v.w;
        g += hv.x * w3v.x + hv.y * w3v.y + hv.z * w3v.z + hv.w * w3v.w;
    }
    f += ab2[0];
    g += ab3[0];
    float s = f * g;
    float mx = s;
    for (int off = 32; off; off >>= 1) mx = fmaxf(mx, __shfl_xor(mx, off));
    float e = expf(s - mx);
    float sum = e;
    for (int off = 32; off; off >>= 1) sum += __shfl_xor(sum, off);
    beta[b * T_ + t] = e / sum;
}

// ---------------------------------------------------------------------------
// out[b,p,n] = b_out[p] + sum_t beta[b,t]*hs1[b,t,n]*W_out[t,p]
// grid 16 blocks (b), 256 threads (2 n each)
// ---------------------------------------------------------------------------
__global__ __launch_bounds__(256) void att_out_kernel(
    const float* __restrict__ hs1, const float* __restrict__ beta,
    const float* __restrict__ Wout, const float* __restrict__ bout,
    float* __restrict__ out) {
    __shared__ float bs[T_];
    __shared__ float ws[T_][P_];
    const int b = blockIdx.x;
    const int tid = threadIdx.x;
    if (tid < T_) bs[tid] = beta[b * T_ + tid];
    for (int i = tid; i < T_ * P_; i += 256) ws[i / P_][i % P_] = Wout[i];
    __syncthreads();
    for (int nn = 0; nn < 2; ++nn) {
        const int n = tid + nn * 256;
        float acc[P_];
#pragma unroll
        for (int p = 0; p < P_; ++p) acc[p] = bout[p];
        for (int t = 0; t < T_; ++t) {
            float v = bs[t] * hs1[((size_t)b * T_ + t) * N_ + n];
#pragma unroll
            for (int p = 0; p < P_; ++p) acc[p] += v * ws[t][p];
        }
#pragma unroll
        for (int p = 0; p < P_; ++p) out[((size_t)b * P_ + p) * N_ + n] = acc[p];
    }
}

extern "C" void kernel_launch(void* const* d_in, const int* in_sizes, int n_in,
                              void* d_out, int out_size, void* d_ws, size_t ws_size,
                              hipStream_t stream) {
    const float* x = (const float*)d_in[0];
    const float* L = (const float*)d_in[1];
    const float* W1 = (const float*)d_in[2];
    const float* b1 = (const float*)d_in[3];
    const float* W2 = (const float*)d_in[4];
    const float* b2 = (const float*)d_in[5];
    const float* aw1 = (const float*)d_in[6];
    const float* aw2 = (const float*)d_in[7];
    const float* aw3 = (const float*)d_in[8];
    const float* ab1 = (const float*)d_in[9];
    const float* ab2 = (const float*)d_in[10];
    const float* ab3 = (const float*)d_in[11];
    const float* Wout = (const float*)d_in[12];
    const float* bout = (const float*)d_in[13];
    float* out = (float*)d_out;

    float* ws = (float*)d_ws;
    float* Lx = ws;                      // B*T*N   = 524288
    float* hs1 = Lx + B_ * T_ * N_;      // B*T*N   = 524288
    float* hb0 = hs1 + B_ * T_ * N_;     // B*N*H   = 1048576
    float* hb1 = hb0 + (size_t)B_ * NH;  // B*N*H
    float* rh = hb1 + (size_t)B_ * NH;   // B*N*H
    float* u = rh + (size_t)B_ * NH;     // B*N*H
    float* beta = u + (size_t)B_ * NH;   // B*T = 1024
    (void)in_sizes; (void)n_in; (void)out_size; (void)ws_size; (void)beta;

    // h0 = 0
    hipMemsetAsync(hb0, 0, (size_t)B_ * NH * sizeof(float), stream);
    // precompute L @ x_t for all t
    lx_kernel<<<256, 512, 0, stream>>>(x, L, Lx);

    for (int t = 0; t < T_; ++t) {
        float* hp = (t & 1) ? hb1 : hb0;
        float* hn = (t & 1) ? hb0 : hb1;
        gc1_kernel<<<256, 512, 0, stream>>>(L, hp, Lx, W1, b1, rh, u, t);
        gc2_kernel<<<256, 512, 0, stream>>>(L, hp, rh, u, Lx, W2, b2, aw1, ab1,
                                            hn, hs1, t);
    }
    att_beta_kernel<<<16, 64, 0, stream>>>(hs1, aw2, aw3, ab2, ab3, beta);
    att_out_kernel<<<16, 256, 0, stream>>>(hs1, beta, Wout, bout, out);
}

// Round 2
// 4316.613 us; speedup vs baseline: 1.0711x; 1.0711x over previous
//
#include <hip/hip_runtime.h>
#include <math.h>

#define B_ 16
#define T_ 64
#define N_ 512
#define H_ 128
#define P_ 12
#define NH 65536  // N_*H_

// ---------------------------------------------------------------------------
// Lx[b,t,m] = sum_n L[m,n] * x[b,t,n]   (L symmetric)
// ---------------------------------------------------------------------------
__global__ __launch_bounds__(512) void lx_kernel(const float* __restrict__ x,
                                                 const float* __restrict__ L,
                                                 float* __restrict__ Lx) {
    __shared__ __align__(16) float xs[4][N_];
    const int r0 = blockIdx.x * 4;
    const int tid = threadIdx.x;
    for (int j = 0; j < 4; ++j)
        xs[j][tid] = x[(size_t)(r0 + j) * N_ + tid];
    __syncthreads();
    float a0 = 0.f, a1 = 0.f, a2 = 0.f, a3 = 0.f;
    const int m = tid;
#pragma unroll 8
    for (int n = 0; n < N_; ++n) {
        float lv = L[(size_t)n * N_ + m];
        a0 += xs[0][n] * lv;
        a1 += xs[1][n] * lv;
        a2 += xs[2][n] * lv;
        a3 += xs[3][n] * lv;
    }
    Lx[(size_t)(r0 + 0) * N_ + m] = a0;
    Lx[(size_t)(r0 + 1) * N_ + m] = a1;
    Lx[(size_t)(r0 + 2) * N_ + m] = a2;
    Lx[(size_t)(r0 + 3) * N_ + m] = a3;
}

// ---------------------------------------------------------------------------
// Kernel A (graph_conv1 + sigmoid + split).
// Phase 1: Z = L @ Hprev, k-split x4, L staged transposed [k][m] (broadcast reads).
// Phase 2: (sum of Z partials) @ W1[1:], W staged in LDS chunks.
// ---------------------------------------------------------------------------
__global__ __launch_bounds__(512) void gc1_kernel(
    const float* __restrict__ L, const float* __restrict__ Hprev,
    const float* __restrict__ Lx, const float* __restrict__ W1,
    const float* __restrict__ b1, float* __restrict__ rh,
    float* __restrict__ u, int t) {
    union Sm {
        struct { float Ht[2][64][128]; float Lt[2][64][36]; } p;  // 83968 B
        float Wt[32][260];                                        // 33280 B
    };
    __shared__ __align__(16) Sm sm;
    __shared__ __align__(16) float Zs[4][32][128];                // 65536 B

    const int tid = threadIdx.x;
    const int b = blockIdx.x >> 4;
    const int m0 = (blockIdx.x & 15) * 32;
    const int g = tid >> 7;        // k-group 0..3
    const int gt = tid & 127;
    const int tx = gt & 31, ty = gt >> 5;
    const int c0 = tx * 4;

    const float* __restrict__ Hb = Hprev + (size_t)b * NH;

    // staging index precompute (constant across chunks)
    const int hrow = tid >> 5, hcol = (tid & 31) * 4;  // H: 64 rows x 128 cols
    const int lm = tid >> 4, lk0 = (tid & 15) * 4;     // L: 32 m x 64 k (transposed store)

    // ---- stage chunk 0
    {
#pragma unroll
        for (int jj = 0; jj < 4; ++jj)
            *(float4*)&sm.p.Ht[0][hrow + 16 * jj][hcol] =
                *(const float4*)&Hb[(size_t)(hrow + 16 * jj) * H_ + hcol];
        float4 lv = *(const float4*)&L[(size_t)(m0 + lm) * N_ + lk0];
        sm.p.Lt[0][lk0 + 0][lm] = lv.x;
        sm.p.Lt[0][lk0 + 1][lm] = lv.y;
        sm.p.Lt[0][lk0 + 2][lm] = lv.z;
        sm.p.Lt[0][lk0 + 3][lm] = lv.w;
    }
    __syncthreads();

    float acc[8][4] = {};

    for (int kc = 0; kc < 8; ++kc) {
        const int bi = kc & 1, bj = bi ^ 1;
        float4 h0, h1, h2, h3, lv;
        if (kc < 7) {
            const size_t kb2 = (size_t)(kc + 1) * 64;
            h0 = *(const float4*)&Hb[(kb2 + hrow) * H_ + hcol];
            h1 = *(const float4*)&Hb[(kb2 + hrow + 16) * H_ + hcol];
            h2 = *(const float4*)&Hb[(kb2 + hrow + 32) * H_ + hcol];
            h3 = *(const float4*)&Hb[(kb2 + hrow + 48) * H_ + hcol];
            lv = *(const float4*)&L[(size_t)(m0 + lm) * N_ + kb2 + lk0];
        }
#pragma unroll
        for (int kk = 0; kk < 16; ++kk) {
            const int k = g * 16 + kk;
            const float4 la = *(const float4*)&sm.p.Lt[bi][k][ty * 8];
            const float4 lb = *(const float4*)&sm.p.Lt[bi][k][ty * 8 + 4];
            const float4 hv = *(const float4*)&sm.p.Ht[bi][k][c0];
#define FMA_ROW(r, s)                                                   \
            acc[r][0] += (s) * hv.x; acc[r][1] += (s) * hv.y;           \
            acc[r][2] += (s) * hv.z; acc[r][3] += (s) * hv.w;
            FMA_ROW(0, la.x) FMA_ROW(1, la.y) FMA_ROW(2, la.z) FMA_ROW(3, la.w)
            FMA_ROW(4, lb.x) FMA_ROW(5, lb.y) FMA_ROW(6, lb.z) FMA_ROW(7, lb.w)
#undef FMA_ROW
        }
        if (kc < 7) {
            *(float4*)&sm.p.Ht[bj][hrow][hcol] = h0;
            *(float4*)&sm.p.Ht[bj][hrow + 16][hcol] = h1;
            *(float4*)&sm.p.Ht[bj][hrow + 32][hcol] = h2;
            *(float4*)&sm.p.Ht[bj][hrow + 48][hcol] = h3;
            sm.p.Lt[bj][lk0 + 0][lm] = lv.x;
            sm.p.Lt[bj][lk0 + 1][lm] = lv.y;
            sm.p.Lt[bj][lk0 + 2][lm] = lv.z;
            sm.p.Lt[bj][lk0 + 3][lm] = lv.w;
        }
        __syncthreads();
    }

    // write k-split partials
#pragma unroll
    for (int r = 0; r < 8; ++r)
        *(float4*)&Zs[g][ty * 8 + r][c0] =
            make_float4(acc[r][0], acc[r][1], acc[r][2], acc[r][3]);
    __syncthreads();

    // reduce 4 partials into Zs[0]
    for (int j = tid; j < 1024; j += 512) {
        const int m = j >> 5, cc = (j & 31) * 4;
        float4 z0 = *(const float4*)&Zs[0][m][cc];
        float4 z1 = *(const float4*)&Zs[1][m][cc];
        float4 z2 = *(const float4*)&Zs[2][m][cc];
        float4 z3 = *(const float4*)&Zs[3][m][cc];
        *(float4*)&Zs[0][m][cc] = make_float4(z0.x + z1.x + z2.x + z3.x,
                                              z0.y + z1.y + z2.y + z3.y,
                                              z0.z + z1.z + z2.z + z3.z,
                                              z0.w + z1.w + z2.w + z3.w);
    }
    __syncthreads();

    // ---- phase 2: out = Z @ W1[1:,:]  (W staged in LDS, 32-ch chunks)
    const int to = tid & 63, tm = tid >> 6;
    const int o0 = to * 4;
    float a2[4][4] = {};
    const int wr = tid >> 4, wc = (tid & 15) * 16;

    for (int c4 = 0; c4 < 4; ++c4) {
#pragma unroll
        for (int jj = 0; jj < 4; ++jj)
            *(float4*)&sm.Wt[wr][wc + 4 * jj] =
                *(const float4*)&W1[(size_t)(1 + c4 * 32 + wr) * 256 + wc + 4 * jj];
        __syncthreads();
#pragma unroll
        for (int ch4 = 0; ch4 < 8; ++ch4) {
            const float4 w0v = *(const float4*)&sm.Wt[ch4 * 4 + 0][o0];
            const float4 w1v = *(const float4*)&sm.Wt[ch4 * 4 + 1][o0];
            const float4 w2v = *(const float4*)&sm.Wt[ch4 * 4 + 2][o0];
            const float4 w3v = *(const float4*)&sm.Wt[ch4 * 4 + 3][o0];
#pragma unroll
            for (int i = 0; i < 4; ++i) {
                const float4 zv = *(const float4*)&Zs[0][tm + 8 * i][c4 * 32 + ch4 * 4];
                a2[i][0] += zv.x * w0v.x + zv.y * w1v.x + zv.z * w2v.x + zv.w * w3v.x;
                a2[i][1] += zv.x * w0v.y + zv.y * w1v.y + zv.z * w2v.y + zv.w * w3v.y;
                a2[i][2] += zv.x * w0v.z + zv.y * w1v.z + zv.z * w2v.z + zv.w * w3v.z;
                a2[i][3] += zv.x * w0v.w + zv.y * w1v.w + zv.z * w2v.w + zv.w * w3v.w;
            }
        }
        __syncthreads();
    }

    // ---- epilogue (verbatim from verified round-1 kernel)
    const float4 w0r = *(const float4*)&W1[o0];   // row 0 (x channel)
    const float4 bbv = *(const float4*)&b1[o0];
    const float* __restrict__ LxRow = Lx + ((size_t)b * T_ + t) * N_ + m0;
    float* __restrict__ rhB = rh + (size_t)b * NH;
    float* __restrict__ uB = u + (size_t)b * NH;
    const bool isR = (m0 < 256);
#pragma unroll
    for (int i = 0; i < 4; ++i) {
        const int mi = tm + 8 * i;
        const float lx = LxRow[mi];
        float v0 = a2[i][0] + lx * w0r.x + bbv.x;
        float v1 = a2[i][1] + lx * w0r.y + bbv.y;
        float v2 = a2[i][2] + lx * w0r.z + bbv.z;
        float v3 = a2[i][3] + lx * w0r.w + bbv.w;
        float s0 = 1.f / (1.f + expf(-v0));
        float s1 = 1.f / (1.f + expf(-v1));
        float s2 = 1.f / (1.f + expf(-v2));
        float s3 = 1.f / (1.f + expf(-v3));
        const int fl = (m0 + mi) * 256 + o0;
        if (isR) {
            float4 hv = *(const float4*)&Hb[fl];
            *(float4*)&rhB[fl] = make_float4(s0 * hv.x, s1 * hv.y, s2 * hv.z, s3 * hv.w);
        } else {
            *(float4*)&uB[fl - NH] = make_float4(s0, s1, s2, s3);
        }
    }
}

// ---------------------------------------------------------------------------
// Kernel B (graph_conv2 + tanh + GRU blend + hs1 row-reduction).
// Same phase-1/phase-2 structure; O=128.
// ---------------------------------------------------------------------------
__global__ __launch_bounds__(512) void gc2_kernel(
    const float* __restrict__ L, const float* __restrict__ Hprev,
    const float* __restrict__ rh, const float* __restrict__ u,
    const float* __restrict__ Lx, const float* __restrict__ W2,
    const float* __restrict__ b2, const float* __restrict__ aw1,
    const float* __restrict__ ab1, float* __restrict__ Hnew,
    float* __restrict__ hs1, int t) {
    union Sm {
        struct { float Ht[2][64][128]; float Lt[2][64][36]; } p;  // 83968 B
        float Wt[32][132];                                        // 16896 B
    };
    __shared__ __align__(16) Sm sm;
    __shared__ __align__(16) float Zs[4][32][128];                // 65536 B
    __shared__ __align__(16) float red[32][32];                   // 4096 B

    const int tid = threadIdx.x;
    const int b = blockIdx.x >> 4;
    const int m0 = (blockIdx.x & 15) * 32;
    const int g = tid >> 7;
    const int gt = tid & 127;
    const int tx = gt & 31, ty = gt >> 5;
    const int c0 = tx * 4;

    const float* __restrict__ Rb = rh + (size_t)b * NH;
    const float* __restrict__ Hb = Hprev + (size_t)b * NH;
    const float* __restrict__ Ub = u + (size_t)b * NH;

    const int hrow = tid >> 5, hcol = (tid & 31) * 4;
    const int lm = tid >> 4, lk0 = (tid & 15) * 4;

    {
#pragma unroll
        for (int jj = 0; jj < 4; ++jj)
            *(float4*)&sm.p.Ht[0][hrow + 16 * jj][hcol] =
                *(const float4*)&Rb[(size_t)(hrow + 16 * jj) * H_ + hcol];
        float4 lv = *(const float4*)&L[(size_t)(m0 + lm) * N_ + lk0];
        sm.p.Lt[0][lk0 + 0][lm] = lv.x;
        sm.p.Lt[0][lk0 + 1][lm] = lv.y;
        sm.p.Lt[0][lk0 + 2][lm] = lv.z;
        sm.p.Lt[0][lk0 + 3][lm] = lv.w;
    }
    __syncthreads();

    float acc[8][4] = {};

    for (int kc = 0; kc < 8; ++kc) {
        const int bi = kc & 1, bj = bi ^ 1;
        float4 h0, h1, h2, h3, lv;
        if (kc < 7) {
            const size_t kb2 = (size_t)(kc + 1) * 64;
            h0 = *(const float4*)&Rb[(kb2 + hrow) * H_ + hcol];
            h1 = *(const float4*)&Rb[(kb2 + hrow + 16) * H_ + hcol];
            h2 = *(const float4*)&Rb[(kb2 + hrow + 32) * H_ + hcol];
            h3 = *(const float4*)&Rb[(kb2 + hrow + 48) * H_ + hcol];
            lv = *(const float4*)&L[(size_t)(m0 + lm) * N_ + kb2 + lk0];
        }
#pragma unroll
        for (int kk = 0; kk < 16; ++kk) {
            const int k = g * 16 + kk;
            const float4 la = *(const float4*)&sm.p.Lt[bi][k][ty * 8];
            const float4 lb = *(const float4*)&sm.p.Lt[bi][k][ty * 8 + 4];
            const float4 hv = *(const float4*)&sm.p.Ht[bi][k][c0];
#define FMA_ROW(r, s)                                                   \
            acc[r][0] += (s) * hv.x; acc[r][1] += (s) * hv.y;           \
            acc[r][2] += (s) * hv.z; acc[r][3] += (s) * hv.w;
            FMA_ROW(0, la.x) FMA_ROW(1, la.y) FMA_ROW(2, la.z) FMA_ROW(3, la.w)
            FMA_ROW(4, lb.x) FMA_ROW(5, lb.y) FMA_ROW(6, lb.z) FMA_ROW(7, lb.w)
#undef FMA_ROW
        }
        if (kc < 7) {
            *(float4*)&sm.p.Ht[bj][hrow][hcol] = h0;
            *(float4*)&sm.p.Ht[bj][hrow + 16][hcol] = h1;
            *(float4*)&sm.p.Ht[bj][hrow + 32][hcol] = h2;
            *(float4*)&sm.p.Ht[bj][hrow + 48][hcol] = h3;
            sm.p.Lt[bj][lk0 + 0][lm] = lv.x;
            sm.p.Lt[bj][lk0 + 1][lm] = lv.y;
            sm.p.Lt[bj][lk0 + 2][lm] = lv.z;
            sm.p.Lt[bj][lk0 + 3][lm] = lv.w;
        }
        __syncthreads();
    }

#pragma unroll
    for (int r = 0; r < 8; ++r)
        *(float4*)&Zs[g][ty * 8 + r][c0] =
            make_float4(acc[r][0], acc[r][1], acc[r][2], acc[r][3]);
    __syncthreads();

    for (int j = tid; j < 1024; j += 512) {
        const int m = j >> 5, cc = (j & 31) * 4;
        float4 z0 = *(const float4*)&Zs[0][m][cc];
        float4 z1 = *(const float4*)&Zs[1][m][cc];
        float4 z2 = *(const float4*)&Zs[2][m][cc];
        float4 z3 = *(const float4*)&Zs[3][m][cc];
        *(float4*)&Zs[0][m][cc] = make_float4(z0.x + z1.x + z2.x + z3.x,
                                              z0.y + z1.y + z2.y + z3.y,
                                              z0.z + z1.z + z2.z + z3.z,
                                              z0.w + z1.w + z2.w + z3.w);
    }
    __syncthreads();

    // ---- phase 2: o range 128
    const int to = tid & 31, tm = tid >> 5;
    const int o0 = to * 4;
    float a2[2][4] = {};
    const int wr = tid >> 4, wc = (tid & 15) * 8;

    for (int c4 = 0; c4 < 4; ++c4) {
#pragma unroll
        for (int jj = 0; jj < 2; ++jj)
            *(float4*)&sm.Wt[wr][wc + 4 * jj] =
                *(const float4*)&W2[(size_t)(1 + c4 * 32 + wr) * H_ + wc + 4 * jj];
        __syncthreads();
#pragma unroll
        for (int ch4 = 0; ch4 < 8; ++ch4) {
            const float4 w0v = *(const float4*)&sm.Wt[ch4 * 4 + 0][o0];
            const float4 w1v = *(const float4*)&sm.Wt[ch4 * 4 + 1][o0];
            const float4 w2v = *(const float4*)&sm.Wt[ch4 * 4 + 2][o0];
            const float4 w3v = *(const float4*)&sm.Wt[ch4 * 4 + 3][o0];
#pragma unroll
            for (int i = 0; i < 2; ++i) {
                const float4 zv = *(const float4*)&Zs[0][tm + 16 * i][c4 * 32 + ch4 * 4];
                a2[i][0] += zv.x * w0v.x + zv.y * w1v.x + zv.z * w2v.x + zv.w * w3v.x;
                a2[i][1] += zv.x * w0v.y + zv.y * w1v.y + zv.z * w2v.y + zv.w * w3v.y;
                a2[i][2] += zv.x * w0v.z + zv.y * w1v.z + zv.z * w2v.z + zv.w * w3v.z;
                a2[i][3] += zv.x * w0v.w + zv.y * w1v.w + zv.z * w2v.w + zv.w * w3v.w;
            }
        }
        __syncthreads();
    }

    // ---- epilogue (verbatim from verified round-1 kernel)
    const float4 w0r = *(const float4*)&W2[o0];
    const float4 bbv = *(const float4*)&b2[o0];
    const float4 awv = *(const float4*)&aw1[o0];
    const float* __restrict__ LxRow = Lx + ((size_t)b * T_ + t) * N_ + m0;
    float* __restrict__ HnB = Hnew + (size_t)b * NH;
#pragma unroll
    for (int i = 0; i < 2; ++i) {
        const int mi = tm + 16 * i;
        const float lx = LxRow[mi];
        float c0e = tanhf(a2[i][0] + lx * w0r.x + bbv.x);
        float c1e = tanhf(a2[i][1] + lx * w0r.y + bbv.y);
        float c2e = tanhf(a2[i][2] + lx * w0r.z + bbv.z);
        float c3e = tanhf(a2[i][3] + lx * w0r.w + bbv.w);
        const int fl = (m0 + mi) * H_ + o0;
        float4 uv = *(const float4*)&Ub[fl];
        float4 hp = *(const float4*)&Hb[fl];
        float h0 = uv.x * hp.x + (1.f - uv.x) * c0e;
        float h1 = uv.y * hp.y + (1.f - uv.y) * c1e;
        float h2 = uv.z * hp.z + (1.f - uv.z) * c2e;
        float h3 = uv.w * hp.w + (1.f - uv.w) * c3e;
        *(float4*)&HnB[fl] = make_float4(h0, h1, h2, h3);
        red[mi][to] = h0 * awv.x + h1 * awv.y + h2 * awv.z + h3 * awv.w;
    }
    __syncthreads();
    if (tid < 32) {
        float s = 0.f;
#pragma unroll
        for (int k2 = 0; k2 < 32; ++k2) s += red[tid][k2];
        hs1[((size_t)b * T_ + t) * N_ + m0 + tid] = s + ab1[0];
    }
}

// ---------------------------------------------------------------------------
// beta[b,t] = softmax_t( (hs1@aw2+ab2) * (hs1@aw3+ab3) )
// ---------------------------------------------------------------------------
__global__ __launch_bounds__(64) void att_beta_kernel(
    const float* __restrict__ hs1, const float* __restrict__ aw2,
    const float* __restrict__ aw3, const float* __restrict__ ab2,
    const float* __restrict__ ab3, float* __restrict__ beta) {
    const int b = blockIdx.x;
    const int t = threadIdx.x;
    const float* __restrict__ row = hs1 + ((size_t)b * T_ + t) * N_;
    float f = 0.f, g = 0.f;
    for (int n = 0; n < N_; n += 4) {
        float4 hv = *(const float4*)&row[n];
        float4 w2v = *(const float4*)&aw2[n];
        float4 w3v = *(const float4*)&aw3[n];
        f += hv.x * w2v.x + hv.y * w2v.y + hv.z * w2v.z + hv.w * w2v.w;
        g += hv.x * w3v.x + hv.y * w3v.y + hv.z * w3v.z + hv.w * w3v.w;
    }
    f += ab2[0];
    g += ab3[0];
    float s = f * g;
    float mx = s;
    for (int off = 32; off; off >>= 1) mx = fmaxf(mx, __shfl_xor(mx, off));
    float e = expf(s - mx);
    float sum = e;
    for (int off = 32; off; off >>= 1) sum += __shfl_xor(sum, off);
    beta[b * T_ + t] = e / sum;
}

// ---------------------------------------------------------------------------
// out[b,p,n] = b_out[p] + sum_t beta[b,t]*hs1[b,t,n]*W_out[t,p]
// ---------------------------------------------------------------------------
__global__ __launch_bounds__(256) void att_out_kernel(
    const float* __restrict__ hs1, const float* __restrict__ beta,
    const float* __restrict__ Wout, const float* __restrict__ bout,
    float* __restrict__ out) {
    __shared__ float bs[T_];
    __shared__ float ws[T_][P_];
    const int b = blockIdx.x;
    const int tid = threadIdx.x;
    if (tid < T_) bs[tid] = beta[b * T_ + tid];
    for (int i = tid; i < T_ * P_; i += 256) ws[i / P_][i % P_] = Wout[i];
    __syncthreads();
    for (int nn = 0; nn < 2; ++nn) {
        const int n = tid + nn * 256;
        float acc[P_];
#pragma unroll
        for (int p = 0; p < P_; ++p) acc[p] = bout[p];
        for (int t = 0; t < T_; ++t) {
            float v = bs[t] * hs1[((size_t)b * T_ + t) * N_ + n];
#pragma unroll
            for (int p = 0; p < P_; ++p) acc[p] += v * ws[t][p];
        }
#pragma unroll
        for (int p = 0; p < P_; ++p) out[((size_t)b * P_ + p) * N_ + n] = acc[p];
    }
}

extern "C" void kernel_launch(void* const* d_in, const int* in_sizes, int n_in,
                              void* d_out, int out_size, void* d_ws, size_t ws_size,
                              hipStream_t stream) {
    const float* x = (const float*)d_in[0];
    const float* L = (const float*)d_in[1];
    const float* W1 = (const float*)d_in[2];
    const float* b1 = (const float*)d_in[3];
    const float* W2 = (const float*)d_in[4];
    const float* b2 = (const float*)d_in[5];
    const float* aw1 = (const float*)d_in[6];
    const float* aw2 = (const float*)d_in[7];
    const float* aw3 = (const float*)d_in[8];
    const float* ab1 = (const float*)d_in[9];
    const float* ab2 = (const float*)d_in[10];
    const float* ab3 = (const float*)d_in[11];
    const float* Wout = (const float*)d_in[12];
    const float* bout = (const float*)d_in[13];
    float* out = (float*)d_out;

    float* ws = (float*)d_ws;
    float* Lx = ws;                      // B*T*N
    float* hs1 = Lx + B_ * T_ * N_;      // B*T*N
    float* hb0 = hs1 + B_ * T_ * N_;     // B*N*H
    float* hb1 = hb0 + (size_t)B_ * NH;  // B*N*H
    float* rh = hb1 + (size_t)B_ * NH;   // B*N*H
    float* u = rh + (size_t)B_ * NH;     // B*N*H
    float* beta = u + (size_t)B_ * NH;   // B*T
    (void)in_sizes; (void)n_in; (void)out_size; (void)ws_size;

    hipMemsetAsync(hb0, 0, (size_t)B_ * NH * sizeof(float), stream);
    lx_kernel<<<256, 512, 0, stream>>>(x, L, Lx);

    for (int t = 0; t < T_; ++t) {
        float* hp = (t & 1) ? hb1 : hb0;
        float* hn = (t & 1) ? hb0 : hb1;
        gc1_kernel<<<256, 512, 0, stream>>>(L, hp, Lx, W1, b1, rh, u, t);
        gc2_kernel<<<256, 512, 0, stream>>>(L, hp, rh, u, Lx, W2, b2, aw1, ab1,
                                            hn, hs1, t);
    }
    att_beta_kernel<<<16, 64, 0, stream>>>(hs1, aw2, aw3, ab2, ab3, beta);
    att_out_kernel<<<16, 256, 0, stream>>>(hs1, beta, Wout, bout, out);
}